// Round 5
// baseline (182.540 us; speedup 1.0000x reference)
//
#include <hip/hip_runtime.h>
#include <hip/hip_bf16.h>

constexpr int D        = 100;
constexpr int K        = 20;
constexpr int N_USER   = 50000;
constexpr int N_ENTITY = 60000;
constexpr int N_NEWS   = 20000;
constexpr int NNZ      = 500000;
constexpr int CAP      = 32;     // bucket capacity per user (avg degree = 10)
constexpr int N_NODE   = N_NEWS + N_ENTITY;
constexpr int TS       = 128;    // padded bf16 row stride (elems) = 256 B = 2 lines

// ---- bf16 helpers ---------------------------------------------------------
static __device__ __forceinline__ unsigned short f2b(float x) {
    union { float f; unsigned int u; } c; c.f = x;
    unsigned int u = c.u;
    return (unsigned short)((u + 0x7FFFu + ((u >> 16) & 1u)) >> 16);
}
static __device__ __forceinline__ float blo(unsigned int t) {
    union { unsigned int u; float f; } c; c.u = t << 16; return c.f;
}
static __device__ __forceinline__ float bhi(unsigned int t) {
    union { unsigned int u; float f; } c; c.u = t & 0xFFFF0000u; return c.f;
}

// ---------------------------------------------------------------------------
// prep: f32 -> bf16 padded tables (ent_emb -> entB, all_emb -> allB) + zero
// counts. Table rows padded 100 -> 128 elems; pad slots written as zeros.
// ---------------------------------------------------------------------------
constexpr int CVT_T = N_ENTITY * 32;   // one thread per ushort4 slot (32/row)

__global__ __launch_bounds__(256) void prep_kernel(
    const float* __restrict__ ent, const float* __restrict__ all,
    ushort4* __restrict__ entB4, ushort4* __restrict__ allB4,
    int* __restrict__ counts)
{
    int i = (int)(blockIdx.x * blockDim.x + threadIdx.x);
    if (i < 2 * CVT_T) {
        const float* src = (i < CVT_T) ? ent : all;
        ushort4*     dst = (i < CVT_T) ? entB4 : allB4;
        int j    = (i < CVT_T) ? i : i - CVT_T;
        int row  = j >> 5;
        int slot = j & 31;
        ushort4 o = make_ushort4(0, 0, 0, 0);
        if (slot < 25) {
            float4 v = *((const float4*)(src + (size_t)row * D) + slot);
            o.x = f2b(v.x); o.y = f2b(v.y); o.z = f2b(v.z); o.w = f2b(v.w);
        }
        dst[(size_t)row * 32 + slot] = o;
    } else {
        int j = i - 2 * CVT_T;
        if (j < N_USER) counts[j] = 0;
    }
}

// ---------------------------------------------------------------------------
// Bucket build: counts + per-entry position + direct (col,val) bucket fill
// ---------------------------------------------------------------------------
__global__ __launch_bounds__(256) void hist_fill2_kernel(
    const int* __restrict__ rows, const int* __restrict__ cols,
    const float* __restrict__ vals,
    int* __restrict__ counts, int* __restrict__ pos_arr,
    int* __restrict__ bcol, float* __restrict__ bval, int nnz)
{
    int j = (int)(blockIdx.x * blockDim.x + threadIdx.x);
    if (j >= nnz) return;
    int r   = __builtin_nontemporal_load(rows + j);
    int pos = atomicAdd(&counts[r], 1);
    pos_arr[j] = pos;
    if (pos < CAP) {
        bcol[(size_t)r * CAP + pos] = __builtin_nontemporal_load(cols + j);
        bval[(size_t)r * CAP + pos] = __builtin_nontemporal_load(vals + j);
    }
}

// ---------------------------------------------------------------------------
// Neighbor-sum aggregation (softmax over size-1 axis == 1.0). bf16 padded
// tables, all-64-lane staged gathers, nt streaming for base/node/idx.
//   row < N_NEWS : table = entB, idx = news_entities
//   else         : table = allB, idx = neigh_entities
// Writes f32 node (nt) + bf16 padded shadow nodeB (incl. zeroed pad).
// ---------------------------------------------------------------------------
__global__ __launch_bounds__(256) void sumagg_kernel(
    const unsigned short* __restrict__ entB,
    const unsigned short* __restrict__ allB,
    const int*   __restrict__ news_ent,
    const int*   __restrict__ ngh_ent,
    const float* __restrict__ all_emb,
    float*       __restrict__ node,
    unsigned short* __restrict__ nodeB)
{
    int row  = (int)((blockIdx.x * blockDim.x + threadIdx.x) >> 6);
    int lane = threadIdx.x & 63;
    if (row >= N_NODE) return;

    const unsigned short* table;
    const int* idxp;
    int brow;
    if (row < N_NEWS) { table = entB; idxp = news_ent + (size_t)row * K; brow = row; }
    else { brow = row - N_NEWS; table = allB; idxp = ngh_ent + (size_t)brow * K; }

    int idxv = (lane < K) ? __builtin_nontemporal_load(idxp + lane) : 0;

    // stage all 20 gathers (row pad is zeros -> all 64 lanes load safely)
    unsigned int t[K];
    #pragma unroll
    for (int k = 0; k < K; ++k) {
        int ei = __shfl(idxv, k);
        t[k] = *(const unsigned int*)(table + (size_t)ei * TS + lane * 2);
    }
    float a0 = 0.f, a1 = 0.f;
    #pragma unroll
    for (int k = 0; k < K; ++k) { a0 += blo(t[k]); a1 += bhi(t[k]); }

    unsigned int packed = 0;
    if (lane < D / 2) {
        const float* bp = all_emb + (size_t)brow * D + lane * 2;
        float b0 = __builtin_nontemporal_load(bp);
        float b1 = __builtin_nontemporal_load(bp + 1);
        float o0 = a0 + b0, o1 = a1 + b1;
        float* np = node + (size_t)row * D + lane * 2;
        __builtin_nontemporal_store(o0, np);
        __builtin_nontemporal_store(o1, np + 1);
        packed = (unsigned int)f2b(o0) | ((unsigned int)f2b(o1) << 16);
    }
    *(unsigned int*)(nodeB + (size_t)row * TS + lane * 2) = packed;
}

// ---------------------------------------------------------------------------
// Per-user aggregate, bf16 padded node gather, batched (8) staged loads:
//   user[u,:] = user_emb[u,:] + sum vals*nodeB[cols,:]
// ---------------------------------------------------------------------------
__global__ __launch_bounds__(256) void user_agg_kernel(
    const int* __restrict__ counts, const int* __restrict__ bcol,
    const float* __restrict__ bval, const unsigned short* __restrict__ nodeB,
    const float* __restrict__ user_emb, float* __restrict__ user)
{
    int u    = (int)((blockIdx.x * blockDim.x + threadIdx.x) >> 6);
    int lane = threadIdx.x & 63;
    if (u >= N_USER) return;

    int c = counts[u];
    if (c > CAP) c = CAP;
    int   colv = (lane < c) ? __builtin_nontemporal_load(bcol + (size_t)u * CAP + lane) : 0;
    float valv = (lane < c) ? __builtin_nontemporal_load(bval + (size_t)u * CAP + lane) : 0.f;

    float a0 = 0.f, a1 = 0.f;
    for (int e0 = 0; e0 < c; e0 += 8) {
        unsigned int t[8]; float v[8];
        #pragma unroll
        for (int e = 0; e < 8; ++e) {
            if (e0 + e < c) {                     // wave-uniform branch
                int col = __shfl(colv, e0 + e);
                v[e]    = __shfl(valv, e0 + e);
                t[e] = *(const unsigned int*)(nodeB + (size_t)col * TS + lane * 2);
            } else { t[e] = 0u; v[e] = 0.f; }
        }
        #pragma unroll
        for (int e = 0; e < 8; ++e) { a0 += v[e] * blo(t[e]); a1 += v[e] * bhi(t[e]); }
    }
    if (lane < D / 2) {
        const float* up = user_emb + (size_t)u * D + lane * 2;
        float u0 = __builtin_nontemporal_load(up);
        float u1 = __builtin_nontemporal_load(up + 1);
        float* op = user + (size_t)u * D + lane * 2;
        __builtin_nontemporal_store(a0 + u0, op);
        __builtin_nontemporal_store(a1 + u1, op + 1);
    }
}

// ---------------------------------------------------------------------------
// Overflow cleanup (entries with pos >= CAP; none expected). f32 node path.
// ---------------------------------------------------------------------------
__global__ __launch_bounds__(256) void overflow_kernel(
    const int* __restrict__ pos_arr, const int* __restrict__ rows,
    const int* __restrict__ cols,    const float* __restrict__ vals,
    const float* __restrict__ node,  float* __restrict__ user, int nnz)
{
    int j = (int)(blockIdx.x * blockDim.x + threadIdx.x);
    if (j >= nnz || pos_arr[j] < CAP) return;
    int   r = rows[j];
    int   c = cols[j];
    float v = vals[j];
    const float* src = node + (size_t)c * D;
    float*       dst = user + (size_t)r * D;
    for (int d = 0; d < D; ++d) unsafeAtomicAdd(&dst[d], v * src[d]);
}

// ---------------------------------------------------------------------------
// Fallback tiers (f32; only if workspace too small — previously sufficient)
// ---------------------------------------------------------------------------
__global__ __launch_bounds__(256) void zero_counts_kernel(int* __restrict__ counts, int n)
{
    int i = (int)(blockIdx.x * blockDim.x + threadIdx.x);
    if (i < n) counts[i] = 0;
}

__global__ __launch_bounds__(256) void sumagg_f32_kernel(
    const float* __restrict__ table, const int* __restrict__ idx_mat,
    const float* __restrict__ base, float* __restrict__ out, int n)
{
    int wave = (int)((blockIdx.x * blockDim.x + threadIdx.x) >> 6);
    int lane = threadIdx.x & 63;
    if (wave >= n) return;
    int idxv = (lane < K) ? idx_mat[(size_t)wave * K + lane] : 0;
    float acc0 = 0.f, acc1 = 0.f;
    int l2 = lane + 64;
    #pragma unroll
    for (int k = 0; k < K; ++k) {
        int ei = __shfl(idxv, k);
        const float* r = table + (size_t)ei * D;
        acc0 += r[lane];
        if (l2 < D) acc1 += r[l2];
    }
    const float* b = base + (size_t)wave * D;
    float*       o = out  + (size_t)wave * D;
    o[lane] = acc0 + b[lane];
    if (l2 < D) o[l2] = acc1 + b[l2];
}

__global__ __launch_bounds__(256) void copy_kernel(
    const float4* __restrict__ src, float4* __restrict__ dst, int n4)
{
    int i = (int)(blockIdx.x * blockDim.x + threadIdx.x);
    if (i < n4) dst[i] = src[i];
}

__global__ __launch_bounds__(256) void scatter_kernel(
    const float* __restrict__ vals, const int* __restrict__ rows,
    const int* __restrict__ cols, const float* __restrict__ node,
    float* __restrict__ user, int nnz)
{
    int j    = (int)((blockIdx.x * blockDim.x + threadIdx.x) >> 6);
    int lane = threadIdx.x & 63;
    if (j >= nnz) return;
    int   r = rows[j];
    int   c = cols[j];
    float v = vals[j];
    const float* src = node + (size_t)c * D;
    float*       dst = user + (size_t)r * D;
    unsafeAtomicAdd(&dst[lane], v * src[lane]);
    int l2 = lane + 64;
    if (l2 < D) unsafeAtomicAdd(&dst[l2], v * src[l2]);
}

__global__ __launch_bounds__(256) void user_agg_f32_kernel(
    const int* __restrict__ counts, const int* __restrict__ bcol,
    const float* __restrict__ bval, const float* __restrict__ node,
    const float* __restrict__ user_emb, float* __restrict__ user)
{
    int u    = (int)((blockIdx.x * blockDim.x + threadIdx.x) >> 6);
    int lane = threadIdx.x & 63;
    if (u >= N_USER) return;
    int c = counts[u];
    if (c > CAP) c = CAP;
    int   colv = (lane < c) ? bcol[(size_t)u * CAP + lane] : 0;
    float valv = (lane < c) ? bval[(size_t)u * CAP + lane] : 0.f;
    float a0 = 0.f, a1 = 0.f;
    int l2 = lane + 64;
    for (int e = 0; e < c; ++e) {
        int   col = __shfl(colv, e);
        float v   = __shfl(valv, e);
        const float* r = node + (size_t)col * D;
        a0 += v * r[lane];
        if (l2 < D) a1 += v * r[l2];
    }
    const float* ue = user_emb + (size_t)u * D;
    float*       o  = user     + (size_t)u * D;
    o[lane] = a0 + ue[lane];
    if (l2 < D) o[l2] = a1 + ue[l2];
}

// ---------------------------------------------------------------------------
extern "C" void kernel_launch(void* const* d_in, const int* in_sizes, int n_in,
                              void* d_out, int out_size, void* d_ws, size_t ws_size,
                              hipStream_t stream)
{
    const float* user_emb = (const float*)d_in[0];
    const float* all_emb  = (const float*)d_in[1];
    const float* ent_emb  = (const float*)d_in[2];
    // d_in[3..7]: relation_emb, W_news, b_news, W_ent, b_ent — dead inputs
    // (softmax over a size-1 axis is identically 1.0 in the reference).
    const float* vals     = (const float*)d_in[8];
    const int*   news_ent = (const int*)d_in[9];
    const int*   ngh_ent  = (const int*)d_in[11];
    const int*   irows    = (const int*)d_in[13];
    const int*   icols    = (const int*)d_in[14];

    float* node = (float*)d_out;                         // 80000 x 100
    float* user = (float*)d_out + (size_t)N_NODE * D;    // 50000 x 100

    // workspace layout (tier A)
    int*   counts  = (int*)d_ws;                              // N_USER
    int*   pos_arr = counts + N_USER;                         // NNZ
    int*   bcol    = pos_arr + NNZ;                           // N_USER*CAP
    float* bval    = (float*)(bcol + (size_t)N_USER * CAP);   // N_USER*CAP
    unsigned short* entB  = (unsigned short*)(bval + (size_t)N_USER * CAP); // N_ENTITY*TS
    unsigned short* allB  = entB + (size_t)N_ENTITY * TS;     // N_ENTITY*TS
    unsigned short* nodeB = allB + (size_t)N_ENTITY * TS;     // N_NODE*TS

    size_t need_bucket = ((size_t)N_USER + NNZ + 2ull * N_USER * CAP) * 4ull;
    size_t need_full   = need_bucket +
                         (2ull * N_ENTITY * TS + (size_t)N_NODE * TS) * 2ull;

    if (ws_size >= need_full) {
        // ---- tier A: padded bf16 tables, staged gathers, nt streaming ----
        int prep_n = 2 * CVT_T + N_USER;
        prep_kernel<<<(prep_n + 255) / 256, 256, 0, stream>>>(
            ent_emb, all_emb, (ushort4*)entB, (ushort4*)allB, counts);
        hist_fill2_kernel<<<(NNZ + 255) / 256, 256, 0, stream>>>(
            irows, icols, vals, counts, pos_arr, bcol, bval, NNZ);
        sumagg_kernel<<<(N_NODE + 3) / 4, 256, 0, stream>>>(
            entB, allB, news_ent, ngh_ent, all_emb, node, nodeB);
        user_agg_kernel<<<(N_USER + 3) / 4, 256, 0, stream>>>(
            counts, bcol, bval, nodeB, user_emb, user);
        overflow_kernel<<<(NNZ + 255) / 256, 256, 0, stream>>>(
            pos_arr, irows, icols, vals, node, user, NNZ);
    } else if (ws_size >= need_bucket) {
        // ---- tier B: f32 bucket-gather ----
        sumagg_f32_kernel<<<(N_NEWS + 3) / 4, 256, 0, stream>>>(
            ent_emb, news_ent, all_emb, node, N_NEWS);
        sumagg_f32_kernel<<<(N_ENTITY + 3) / 4, 256, 0, stream>>>(
            all_emb, ngh_ent, all_emb, node + (size_t)N_NEWS * D, N_ENTITY);
        zero_counts_kernel<<<(N_USER + 255) / 256, 256, 0, stream>>>(counts, N_USER);
        hist_fill2_kernel<<<(NNZ + 255) / 256, 256, 0, stream>>>(
            irows, icols, vals, counts, pos_arr, bcol, bval, NNZ);
        user_agg_f32_kernel<<<(N_USER + 3) / 4, 256, 0, stream>>>(
            counts, bcol, bval, node, user_emb, user);
        overflow_kernel<<<(NNZ + 255) / 256, 256, 0, stream>>>(
            pos_arr, irows, icols, vals, node, user, NNZ);
    } else {
        // ---- tier C: atomic scatter ----
        sumagg_f32_kernel<<<(N_NEWS + 3) / 4, 256, 0, stream>>>(
            ent_emb, news_ent, all_emb, node, N_NEWS);
        sumagg_f32_kernel<<<(N_ENTITY + 3) / 4, 256, 0, stream>>>(
            all_emb, ngh_ent, all_emb, node + (size_t)N_NEWS * D, N_ENTITY);
        int n4 = N_USER * D / 4;
        copy_kernel<<<(n4 + 255) / 256, 256, 0, stream>>>(
            (const float4*)user_emb, (float4*)user, n4);
        scatter_kernel<<<(NNZ + 3) / 4, 256, 0, stream>>>(
            vals, irows, icols, node, user, NNZ);
    }
}

// Round 6
// 164.116 us; speedup vs baseline: 1.1123x; 1.1123x over previous
//
#include <hip/hip_runtime.h>
#include <hip/hip_bf16.h>

constexpr int D        = 100;
constexpr int K        = 20;
constexpr int N_USER   = 50000;
constexpr int N_ENTITY = 60000;
constexpr int N_NEWS   = 20000;
constexpr int NNZ      = 500000;
constexpr int CAP      = 32;     // bucket capacity per user (avg degree = 10)
constexpr int N_NODE   = N_NEWS + N_ENTITY;
constexpr int TS       = 128;    // padded bf16 row stride (elems) = 256 B = 2 lines

// ---- bf16 helpers ---------------------------------------------------------
static __device__ __forceinline__ unsigned short f2b(float x) {
    union { float f; unsigned int u; } c; c.f = x;
    unsigned int u = c.u;
    return (unsigned short)((u + 0x7FFFu + ((u >> 16) & 1u)) >> 16);
}
static __device__ __forceinline__ float blo(unsigned int t) {
    union { unsigned int u; float f; } c; c.u = t << 16; return c.f;
}
static __device__ __forceinline__ float bhi(unsigned int t) {
    union { unsigned int u; float f; } c; c.u = t & 0xFFFF0000u; return c.f;
}

// ---------------------------------------------------------------------------
// prep: f32 -> bf16 padded tables (ent_emb -> entB, all_emb -> allB) + zero
// counts. Table rows padded 100 -> 128 elems; pad slots written as zeros.
// ---------------------------------------------------------------------------
constexpr int CVT_T = N_ENTITY * 32;   // one thread per ushort4 slot (32/row)

__global__ __launch_bounds__(256) void prep_kernel(
    const float* __restrict__ ent, const float* __restrict__ all,
    ushort4* __restrict__ entB4, ushort4* __restrict__ allB4,
    int* __restrict__ counts)
{
    int i = (int)(blockIdx.x * blockDim.x + threadIdx.x);
    if (i < 2 * CVT_T) {
        const float* src = (i < CVT_T) ? ent : all;
        ushort4*     dst = (i < CVT_T) ? entB4 : allB4;
        int j    = (i < CVT_T) ? i : i - CVT_T;
        int row  = j >> 5;
        int slot = j & 31;
        ushort4 o = make_ushort4(0, 0, 0, 0);
        if (slot < 25) {
            const float4* sp = (const float4*)(src + (size_t)row * D) + slot;
            float4 v;
            v.x = __builtin_nontemporal_load(&((const float*)sp)[0]);
            v.y = __builtin_nontemporal_load(&((const float*)sp)[1]);
            v.z = __builtin_nontemporal_load(&((const float*)sp)[2]);
            v.w = __builtin_nontemporal_load(&((const float*)sp)[3]);
            o.x = f2b(v.x); o.y = f2b(v.y); o.z = f2b(v.z); o.w = f2b(v.w);
        }
        dst[(size_t)row * 32 + slot] = o;
    } else {
        int j = i - 2 * CVT_T;
        if (j < N_USER) counts[j] = 0;
    }
}

// ---------------------------------------------------------------------------
// Bucket build: counts + per-entry position + interleaved (col,val) int2 fill
// ---------------------------------------------------------------------------
__global__ __launch_bounds__(256) void hist_fill_kernel(
    const int* __restrict__ rows, const int* __restrict__ cols,
    const float* __restrict__ vals,
    int* __restrict__ counts, int* __restrict__ pos_arr,
    int2* __restrict__ bpair, int nnz)
{
    int j = (int)(blockIdx.x * blockDim.x + threadIdx.x);
    if (j >= nnz) return;
    int r   = __builtin_nontemporal_load(rows + j);
    int pos = atomicAdd(&counts[r], 1);
    pos_arr[j] = pos;
    if (pos < CAP) {
        int   c = __builtin_nontemporal_load(cols + j);
        float v = __builtin_nontemporal_load(vals + j);
        bpair[(size_t)r * CAP + pos] = make_int2(c, __float_as_int(v));
    }
}

// ---------------------------------------------------------------------------
// Neighbor-sum aggregation (softmax over size-1 axis == 1.0). bf16 padded
// table, all-64-lane staged gathers, nt streaming for base/node/idx.
// One kernel per table (news / entity) for L2 temporal locality.
// Writes f32 node (nt) + bf16 padded shadow nodeB (incl. zeroed pad).
// ---------------------------------------------------------------------------
__global__ __launch_bounds__(256) void sumagg_kernel(
    const unsigned short* __restrict__ table,
    const int*   __restrict__ idx_mat,   // n x K
    const float* __restrict__ base,      // f32 residual rows
    float*       __restrict__ node,      // f32 out rows (pre-offset)
    unsigned short* __restrict__ nodeB,  // bf16 shadow rows (pre-offset)
    int n)
{
    int row  = (int)((blockIdx.x * blockDim.x + threadIdx.x) >> 6);
    int lane = threadIdx.x & 63;
    if (row >= n) return;

    const int* idxp = idx_mat + (size_t)row * K;
    int idxv = (lane < K) ? __builtin_nontemporal_load(idxp + lane) : 0;

    // stage all 20 gathers (row pad is zeros -> all 64 lanes load safely)
    unsigned int t[K];
    #pragma unroll
    for (int k = 0; k < K; ++k) {
        int ei = __shfl(idxv, k);
        t[k] = *(const unsigned int*)(table + (size_t)ei * TS + lane * 2);
    }
    float a0 = 0.f, a1 = 0.f;
    #pragma unroll
    for (int k = 0; k < K; ++k) { a0 += blo(t[k]); a1 += bhi(t[k]); }

    unsigned int packed = 0;
    if (lane < D / 2) {
        const float* bp = base + (size_t)row * D + lane * 2;
        float b0 = __builtin_nontemporal_load(bp);
        float b1 = __builtin_nontemporal_load(bp + 1);
        float o0 = a0 + b0, o1 = a1 + b1;
        float* np = node + (size_t)row * D + lane * 2;
        __builtin_nontemporal_store(o0, np);
        __builtin_nontemporal_store(o1, np + 1);
        packed = (unsigned int)f2b(o0) | ((unsigned int)f2b(o1) << 16);
    }
    *(unsigned int*)(nodeB + (size_t)row * TS + lane * 2) = packed;
}

// ---------------------------------------------------------------------------
// Per-user aggregate, bf16 padded node gather. Branch-free batched staging:
// clamped entry index (tail duplicates -> L1 hits) with zeroed weights.
//   user[u,:] = user_emb[u,:] + sum vals*nodeB[cols,:]
// ---------------------------------------------------------------------------
__global__ __launch_bounds__(256) void user_agg_kernel(
    const int* __restrict__ counts, const int2* __restrict__ bpair,
    const unsigned short* __restrict__ nodeB,
    const float* __restrict__ user_emb, float* __restrict__ user)
{
    int u    = (int)((blockIdx.x * blockDim.x + threadIdx.x) >> 6);
    int lane = threadIdx.x & 63;
    if (u >= N_USER) return;

    int c = counts[u];
    if (c > CAP) c = CAP;

    int colv = 0; float valv = 0.f;
    if (lane < c) {
        int2 bp = bpair[(size_t)u * CAP + lane];
        colv = bp.x; valv = __int_as_float(bp.y);
    }

    float a0 = 0.f, a1 = 0.f;
    for (int e0 = 0; e0 < c; e0 += 8) {
        unsigned int t[8]; float v[8];
        #pragma unroll
        for (int e = 0; e < 8; ++e) {
            int ee = e0 + e;
            int es = (ee < c) ? ee : (c - 1);   // clamp: dup loads are L1 hits
            int   col = __shfl(colv, es);
            float vv  = __shfl(valv, es);
            v[e] = (ee < c) ? vv : 0.f;
            t[e] = *(const unsigned int*)(nodeB + (size_t)col * TS + lane * 2);
        }
        #pragma unroll
        for (int e = 0; e < 8; ++e) { a0 += v[e] * blo(t[e]); a1 += v[e] * bhi(t[e]); }
    }
    if (lane < D / 2) {
        const float* up = user_emb + (size_t)u * D + lane * 2;
        float u0 = __builtin_nontemporal_load(up);
        float u1 = __builtin_nontemporal_load(up + 1);
        float* op = user + (size_t)u * D + lane * 2;
        __builtin_nontemporal_store(a0 + u0, op);
        __builtin_nontemporal_store(a1 + u1, op + 1);
    }
}

// ---------------------------------------------------------------------------
// Overflow cleanup (entries with pos >= CAP; none expected). f32 node path.
// ---------------------------------------------------------------------------
__global__ __launch_bounds__(256) void overflow_kernel(
    const int* __restrict__ pos_arr, const int* __restrict__ rows,
    const int* __restrict__ cols,    const float* __restrict__ vals,
    const float* __restrict__ node,  float* __restrict__ user, int nnz)
{
    int j = (int)(blockIdx.x * blockDim.x + threadIdx.x);
    if (j >= nnz || pos_arr[j] < CAP) return;
    int   r = rows[j];
    int   c = cols[j];
    float v = vals[j];
    const float* src = node + (size_t)c * D;
    float*       dst = user + (size_t)r * D;
    for (int d = 0; d < D; ++d) unsafeAtomicAdd(&dst[d], v * src[d]);
}

// ---------------------------------------------------------------------------
// Fallback tiers (f32; only if workspace too small — previously sufficient)
// ---------------------------------------------------------------------------
__global__ __launch_bounds__(256) void zero_counts_kernel(int* __restrict__ counts, int n)
{
    int i = (int)(blockIdx.x * blockDim.x + threadIdx.x);
    if (i < n) counts[i] = 0;
}

__global__ __launch_bounds__(256) void sumagg_f32_kernel(
    const float* __restrict__ table, const int* __restrict__ idx_mat,
    const float* __restrict__ base, float* __restrict__ out, int n)
{
    int wave = (int)((blockIdx.x * blockDim.x + threadIdx.x) >> 6);
    int lane = threadIdx.x & 63;
    if (wave >= n) return;
    int idxv = (lane < K) ? idx_mat[(size_t)wave * K + lane] : 0;
    float acc0 = 0.f, acc1 = 0.f;
    int l2 = lane + 64;
    #pragma unroll
    for (int k = 0; k < K; ++k) {
        int ei = __shfl(idxv, k);
        const float* r = table + (size_t)ei * D;
        acc0 += r[lane];
        if (l2 < D) acc1 += r[l2];
    }
    const float* b = base + (size_t)wave * D;
    float*       o = out  + (size_t)wave * D;
    o[lane] = acc0 + b[lane];
    if (l2 < D) o[l2] = acc1 + b[l2];
}

__global__ __launch_bounds__(256) void copy_kernel(
    const float4* __restrict__ src, float4* __restrict__ dst, int n4)
{
    int i = (int)(blockIdx.x * blockDim.x + threadIdx.x);
    if (i < n4) dst[i] = src[i];
}

__global__ __launch_bounds__(256) void scatter_kernel(
    const float* __restrict__ vals, const int* __restrict__ rows,
    const int* __restrict__ cols, const float* __restrict__ node,
    float* __restrict__ user, int nnz)
{
    int j    = (int)((blockIdx.x * blockDim.x + threadIdx.x) >> 6);
    int lane = threadIdx.x & 63;
    if (j >= nnz) return;
    int   r = rows[j];
    int   c = cols[j];
    float v = vals[j];
    const float* src = node + (size_t)c * D;
    float*       dst = user + (size_t)r * D;
    unsafeAtomicAdd(&dst[lane], v * src[lane]);
    int l2 = lane + 64;
    if (l2 < D) unsafeAtomicAdd(&dst[l2], v * src[l2]);
}

__global__ __launch_bounds__(256) void user_agg_f32_kernel(
    const int* __restrict__ counts, const int2* __restrict__ bpair,
    const float* __restrict__ node,
    const float* __restrict__ user_emb, float* __restrict__ user)
{
    int u    = (int)((blockIdx.x * blockDim.x + threadIdx.x) >> 6);
    int lane = threadIdx.x & 63;
    if (u >= N_USER) return;
    int c = counts[u];
    if (c > CAP) c = CAP;
    int colv = 0; float valv = 0.f;
    if (lane < c) {
        int2 bp = bpair[(size_t)u * CAP + lane];
        colv = bp.x; valv = __int_as_float(bp.y);
    }
    float a0 = 0.f, a1 = 0.f;
    int l2 = lane + 64;
    for (int e = 0; e < c; ++e) {
        int   col = __shfl(colv, e);
        float v   = __shfl(valv, e);
        const float* r = node + (size_t)col * D;
        a0 += v * r[lane];
        if (l2 < D) a1 += v * r[l2];
    }
    const float* ue = user_emb + (size_t)u * D;
    float*       o  = user     + (size_t)u * D;
    o[lane] = a0 + ue[lane];
    if (l2 < D) o[l2] = a1 + ue[l2];
}

// ---------------------------------------------------------------------------
extern "C" void kernel_launch(void* const* d_in, const int* in_sizes, int n_in,
                              void* d_out, int out_size, void* d_ws, size_t ws_size,
                              hipStream_t stream)
{
    const float* user_emb = (const float*)d_in[0];
    const float* all_emb  = (const float*)d_in[1];
    const float* ent_emb  = (const float*)d_in[2];
    // d_in[3..7]: relation_emb, W_news, b_news, W_ent, b_ent — dead inputs
    // (softmax over a size-1 axis is identically 1.0 in the reference).
    const float* vals     = (const float*)d_in[8];
    const int*   news_ent = (const int*)d_in[9];
    const int*   ngh_ent  = (const int*)d_in[11];
    const int*   irows    = (const int*)d_in[13];
    const int*   icols    = (const int*)d_in[14];

    float* node = (float*)d_out;                         // 80000 x 100
    float* user = (float*)d_out + (size_t)N_NODE * D;    // 50000 x 100

    // workspace layout (tier A)
    int*   counts  = (int*)d_ws;                              // N_USER
    int*   pos_arr = counts + N_USER;                         // NNZ
    int2*  bpair   = (int2*)(pos_arr + NNZ);                  // N_USER*CAP int2
    unsigned short* entB  = (unsigned short*)(bpair + (size_t)N_USER * CAP); // N_ENTITY*TS
    unsigned short* allB  = entB + (size_t)N_ENTITY * TS;     // N_ENTITY*TS
    unsigned short* nodeB = allB + (size_t)N_ENTITY * TS;     // N_NODE*TS

    size_t need_bucket = ((size_t)N_USER + NNZ + 2ull * N_USER * CAP) * 4ull;
    size_t need_full   = need_bucket +
                         (2ull * N_ENTITY * TS + (size_t)N_NODE * TS) * 2ull;

    if (ws_size >= need_full) {
        // ---- tier A: padded bf16 tables, staged gathers, nt streaming ----
        int prep_n = 2 * CVT_T + N_USER;
        prep_kernel<<<(prep_n + 255) / 256, 256, 0, stream>>>(
            ent_emb, all_emb, (ushort4*)entB, (ushort4*)allB, counts);
        hist_fill_kernel<<<(NNZ + 255) / 256, 256, 0, stream>>>(
            irows, icols, vals, counts, pos_arr, bpair, NNZ);
        // news phase: gather table = entB only (L2 working set = one table)
        sumagg_kernel<<<(N_NEWS + 3) / 4, 256, 0, stream>>>(
            entB, news_ent, all_emb, node, nodeB, N_NEWS);
        // entity phase: gather table = allB only
        sumagg_kernel<<<(N_ENTITY + 3) / 4, 256, 0, stream>>>(
            allB, ngh_ent, all_emb,
            node + (size_t)N_NEWS * D, nodeB + (size_t)N_NEWS * TS, N_ENTITY);
        user_agg_kernel<<<(N_USER + 3) / 4, 256, 0, stream>>>(
            counts, bpair, nodeB, user_emb, user);
        overflow_kernel<<<(NNZ + 255) / 256, 256, 0, stream>>>(
            pos_arr, irows, icols, vals, node, user, NNZ);
    } else if (ws_size >= need_bucket) {
        // ---- tier B: f32 bucket-gather ----
        sumagg_f32_kernel<<<(N_NEWS + 3) / 4, 256, 0, stream>>>(
            ent_emb, news_ent, all_emb, node, N_NEWS);
        sumagg_f32_kernel<<<(N_ENTITY + 3) / 4, 256, 0, stream>>>(
            all_emb, ngh_ent, all_emb, node + (size_t)N_NEWS * D, N_ENTITY);
        zero_counts_kernel<<<(N_USER + 255) / 256, 256, 0, stream>>>(counts, N_USER);
        hist_fill_kernel<<<(NNZ + 255) / 256, 256, 0, stream>>>(
            irows, icols, vals, counts, pos_arr, bpair, NNZ);
        user_agg_f32_kernel<<<(N_USER + 3) / 4, 256, 0, stream>>>(
            counts, bpair, node, user_emb, user);
        overflow_kernel<<<(NNZ + 255) / 256, 256, 0, stream>>>(
            pos_arr, irows, icols, vals, node, user, NNZ);
    } else {
        // ---- tier C: atomic scatter ----
        sumagg_f32_kernel<<<(N_NEWS + 3) / 4, 256, 0, stream>>>(
            ent_emb, news_ent, all_emb, node, N_NEWS);
        sumagg_f32_kernel<<<(N_ENTITY + 3) / 4, 256, 0, stream>>>(
            all_emb, ngh_ent, all_emb, node + (size_t)N_NEWS * D, N_ENTITY);
        int n4 = N_USER * D / 4;
        copy_kernel<<<(n4 + 255) / 256, 256, 0, stream>>>(
            (const float4*)user_emb, (float4*)user, n4);
        scatter_kernel<<<(NNZ + 3) / 4, 256, 0, stream>>>(
            vals, irows, icols, node, user, NNZ);
    }
}